// Round 11
// baseline (5780.889 us; speedup 1.0000x reference)
//
#include <hip/hip_runtime.h>

#define NWG  56
#define NTHR 384
#define TT   256
#define SPLITF   2048.0f
#define INVSPLIT 4.8828125e-4f

typedef _Float16 f16;
typedef __attribute__((ext_vector_type(8))) _Float16 f16x8;
typedef __attribute__((ext_vector_type(4))) float f32x4;

__device__ __forceinline__ float sigacc(float x){ return 1.0f/(1.0f + expf(-x)); }

// key = [order-preserving f32 : 32][step tag : 16][255-bin : 8]
__device__ __forceinline__ unsigned long long amax_key(float v, int bin, unsigned tag){
  unsigned u = __float_as_uint(v);
  u = (u & 0x80000000u) ? ~u : (u | 0x80000000u);
  return ((unsigned long long)u << 32) | ((unsigned long long)(tag & 0xFFFFu) << 8)
       | (unsigned)(255 - bin);
}

// hp chunk bases {hcr,hcu,hce,hfr,hfu,hfe} = 448*{0,2,4,1,3,5}
__device__ __forceinline__ int grp_base(int g){ return 448 * ((g < 3) ? (2*g) : (2*g - 5)); }

// ---- cross-WG primitives (r4/r7-proven): writes RMW at LLC; polls relaxed agent.
__device__ __forceinline__ void xchg32(unsigned* p, unsigned v){
  __hip_atomic_exchange(p, v, __ATOMIC_RELAXED, __HIP_MEMORY_SCOPE_AGENT);
}
__device__ __forceinline__ void xchg64(unsigned long long* p, unsigned long long v){
  __hip_atomic_exchange(p, v, __ATOMIC_RELAXED, __HIP_MEMORY_SCOPE_AGENT);
}
__device__ __forceinline__ unsigned ldg32(const unsigned* p){
  return __hip_atomic_load(p, __ATOMIC_RELAXED, __HIP_MEMORY_SCOPE_AGENT);
}
__device__ __forceinline__ unsigned long long ldg64(const void* p){
  return __hip_atomic_load((const unsigned long long*)p, __ATOMIC_RELAXED, __HIP_MEMORY_SCOPE_AGENT);
}
__device__ __forceinline__ void drain(){ asm volatile("s_waitcnt vmcnt(0)" ::: "memory"); }
__device__ __forceinline__ int f16bits(f16 h){
  return (int)__builtin_bit_cast(unsigned short, h);
}

// ---- prep: pack GRU weight rows into MFMA A-fragment order, f16 hi/lo split ----
__global__ void pack_gru(const float* __restrict__ W, f16* __restrict__ outH, f16* __restrict__ outL){
  int blk = blockIdx.x;            // ((w*6 + (mt*2+kh))*14 + ks) ; 56*6*14 = 4704
  int ks  = blk % 14;
  int rest= blk / 14;
  int wv  = rest % 6, w = rest / 6;
  int mt  = wv >> 1, kh = wv & 1;
  int l   = threadIdx.x;
  int lr  = mt*16 + (l & 15);
  int R   = grp_base(lr >> 3) + 8*w + (lr & 7);
  int k   = kh*448 + ks*32 + (l >> 4)*8;
  const float* src = W + (size_t)R*896 + k;
  f16x8 vh, vl;
  #pragma unroll
  for (int i=0;i<8;i++){
    float x = src[i];
    f16 h = (f16)x;
    vh[i] = h;
    vl[i] = (f16)((x - (float)h) * SPLITF);
  }
  size_t o = (size_t)blk*64 + l;
  ((f16x8*)outH)[o] = vh;
  ((f16x8*)outL)[o] = vl;
}

// ---- prep: pack bins weights into MFMA B-fragment order, f16 hi/lo split -------
__global__ void pack_bins(const float* __restrict__ Wc, const float* __restrict__ Wf,
                          f16* __restrict__ oCh, f16* __restrict__ oCl,
                          f16* __restrict__ oFh, f16* __restrict__ oFl){
  int blk  = blockIdx.x;           // 2*16*14 = 448
  int half = blk / 224;
  int rem  = blk % 224;            // wg*14 + ks
  int ks   = rem % 14, wg = rem / 14;
  int l    = threadIdx.x;
  const float* W = half ? Wf : Wc;
  f16* oh = half ? oFh : oCh;
  f16* ol = half ? oFl : oCl;
  int bin = wg*16 + (l & 15);
  int k   = ks*32 + (l >> 4)*8;
  const float* src = W + (size_t)bin*448 + k;
  f16x8 vh, vl;
  #pragma unroll
  for (int i=0;i<8;i++){
    float x = src[i];
    f16 h = (f16)x;
    vh[i] = h;
    vl[i] = (f16)((x - (float)h) * SPLITF);
  }
  size_t o = (size_t)rem*64 + l;
  ((f16x8*)oh)[o] = vh;
  ((f16x8*)ol)[o] = vl;
}

// ---------------- main persistent kernel -----------------------------------------
// H layout (u32): [2 bufs][32 batch][56 wg][16]: per 64B chunk:
//   0..3 ch-hi pairs | 4..7 ch-lo | 8..11 fh-hi | 12..15 fh-lo
__launch_bounds__(NTHR, 1)
__global__ void wavernn_main(
    const float* __restrict__ cond,      // [32][256][3][896]
    const float* __restrict__ h0,        // [32][896]
    const float* __restrict__ gib,       // [2688]
    const float* __restrict__ ghb,       // [2688]
    const float* __restrict__ wci,       // [1344][2]
    const float* __restrict__ bci,       // [1344]
    const float* __restrict__ wfi,       // [1344][3]
    const float* __restrict__ bfi,       // [1344]
    const float* __restrict__ bbc,       // [256]
    const float* __restrict__ bbf,       // [256]
    const f16*  __restrict__ wsAh, const f16* __restrict__ wsAl,
    const f16*  __restrict__ wsBCh, const f16* __restrict__ wsBCl,
    const f16*  __restrict__ wsBFh, const f16* __restrict__ wsBFl,
    unsigned*   __restrict__ Hg,         // [2][32][56][16] u32
    unsigned long long* __restrict__ partC,   // [16][32] tagged keys
    unsigned long long* __restrict__ partF,   // [16][32]
    unsigned*   __restrict__ flags,      // fE0 @0, fE1 @1024, fE3 @2048 (u32, stride 16)
    float* __restrict__ out)             // [8192 oc][8192 of][28672 hidden]
{
  __shared__ float hpL[48][33];
  __shared__ float coarseL[32], fineL[32];
  __shared__ f16x8 binBh0[896], binBl0[896], binBh1[896], binBl1[896];
  __shared__ float wclL[3][8][2], bclL[3][8], wflL[3][8][3], bflL[3][8], hblL[48];

  const int w   = blockIdx.x;
  const int tid = threadIdx.x;
  const int wv  = tid >> 6;
  const int l   = tid & 63;
  const int b   = tid >> 3, e = tid & 7;
  const bool owner = tid < 256;
  const int jc  = 8*w + e;

  unsigned* fE0 = flags;
  unsigned* fE1 = flags + 1024;
  unsigned* fE3 = flags + 2048;

  // gemm role: waves 2,3,4 hold kh=0 (ch-half) frags; waves 0,1,5 hold kh=1 (fh-half)
  const int g_kh = (wv >= 2 && wv <= 4) ? 0 : 1;
  const int g_mt = (wv >= 2 && wv <= 4) ? (wv - 2) : (wv == 5 ? 2 : wv);

  // A fragments persistent in VGPRs: 16 rows x half-K, hi+lo
  f16x8 afh[14], afl[14];
  {
    const f16x8* Ah = (const f16x8*)wsAh + (size_t)(w*6 + (g_mt*2 + g_kh))*14*64;
    const f16x8* Al = (const f16x8*)wsAl + (size_t)(w*6 + (g_mt*2 + g_kh))*14*64;
    #pragma unroll
    for (int ks=0; ks<14; ks++){ afh[ks] = Ah[ks*64 + l]; afl[ks] = Al[ks*64 + l]; }
  }
  if (w < 16) {
    const f16x8* s0 = (const f16x8*)wsBCh + (size_t)w*896;
    const f16x8* s1 = (const f16x8*)wsBCl + (size_t)w*896;
    const f16x8* s2 = (const f16x8*)wsBFh + (size_t)w*896;
    const f16x8* s3 = (const f16x8*)wsBFl + (size_t)w*896;
    for (int i = tid; i < 896; i += NTHR) {
      binBh0[i] = s0[i]; binBl0[i] = s1[i];
      binBh1[i] = s2[i]; binBl1[i] = s3[i];
    }
  }
  if (tid < 48) hblL[tid] = ghb[grp_base(tid>>3) + 8*w + (tid&7)];
  if (tid < 24) {
    int p = tid >> 3, ee = tid & 7;
    int j = p*448 + 8*w + ee;
    wclL[p][ee][0] = wci[j*2+0]; wclL[p][ee][1] = wci[j*2+1];
    bclL[p][ee]    = bci[j] + gib[p*896 + 8*w + ee];
    wflL[p][ee][0] = wfi[j*3+0]; wflL[p][ee][1] = wfi[j*3+1]; wflL[p][ee][2] = wfi[j*3+2];
    bflL[p][ee]    = bfi[j] + gib[p*896 + 448 + 8*w + ee];
  }
  if (tid < 32) { coarseL[tid] = 128.0f/127.5f - 1.0f; fineL[tid] = -1.0f; }
  float biasC = 0.f, biasF = 0.f;
  if (w < 16) { biasC = bbc[w*16 + (l&15)]; biasF = bbf[w*16 + (l&15)]; }

  // pack+store into this WG's PRIVATE 64B chunk: 4 xchg64 per publish (e=0,4 lanes)
  auto store_half = [&](unsigned* Hc, int fine, float val){
    f16 hh = (f16)val;
    f16 hl = (f16)((val - (float)hh) * SPLITF);
    int pk = f16bits(hh) | (f16bits(hl) << 16);
    int n1 = __shfl_down(pk, 1);
    int n2 = __shfl_down(pk, 2);
    int n3 = __shfl_down(pk, 3);
    if ((e & 3) == 0) {
      unsigned h0_ = (unsigned)((pk & 0xffff) | (n1 << 16));
      unsigned h1_ = (unsigned)((n2 & 0xffff) | (n3 << 16));
      unsigned l0_ = ((unsigned)pk >> 16) | ((unsigned)n1 & 0xffff0000u);
      unsigned l1_ = ((unsigned)n2 >> 16) | ((unsigned)n3 & 0xffff0000u);
      int q = e >> 2;   // 0 or 1
      xchg64((unsigned long long*)(Hc + fine*8 + q*2),
             (unsigned long long)h0_ | ((unsigned long long)h1_ << 32));
      xchg64((unsigned long long*)(Hc + fine*8 + 4 + q*2),
             (unsigned long long)l0_ | ((unsigned long long)l1_ << 32));
    }
  };

  // flag poll: relaxed until detect, then ONE acquire load -> cache inv, so
  // subsequent PLAIN CACHED loads of the released data are safe (r7-proven).
  auto wait56 = [&](const unsigned* f, int n, unsigned tgt){
    const unsigned* p = f + ((l < n) ? l*16 : 0);
    for(;;){
      unsigned v = ldg32(p);
      if (__all(v == tgt)) break;
      __builtin_amdgcn_s_sleep(1);
    }
    unsigned vv = __hip_atomic_load(p, __ATOMIC_ACQUIRE, __HIP_MEMORY_SCOPE_AGENT);
    asm volatile("" :: "v"(vv) : "memory");
  };
  // direct poll of 16 tagged partials: lane covers batch (l&31), keys off..off+7,
  // cross-half combine via shfl_xor(32). Returns bin for batch (l&31).
  auto poll16 = [&](const unsigned long long* part, unsigned tgt)->int{
    int bb = l & 31, off = (l >> 5)*8;
    unsigned long long k0,k1,k2,k3,k4,k5,k6,k7;
    for(;;){
      k0=ldg64(&part[(off+0)*32+bb]); k1=ldg64(&part[(off+1)*32+bb]);
      k2=ldg64(&part[(off+2)*32+bb]); k3=ldg64(&part[(off+3)*32+bb]);
      k4=ldg64(&part[(off+4)*32+bb]); k5=ldg64(&part[(off+5)*32+bb]);
      k6=ldg64(&part[(off+6)*32+bb]); k7=ldg64(&part[(off+7)*32+bb]);
      unsigned long long tmask = 0xFFFF00ull, texp = (unsigned long long)tgt << 8;
      bool ok = ((k0&tmask)==texp) & ((k1&tmask)==texp) & ((k2&tmask)==texp) & ((k3&tmask)==texp)
              & ((k4&tmask)==texp) & ((k5&tmask)==texp) & ((k6&tmask)==texp) & ((k7&tmask)==texp);
      if (__all(ok)) break;
      __builtin_amdgcn_s_sleep(1);
    }
    unsigned long long m01=k0>k1?k0:k1, m23=k2>k3?k2:k3, m45=k4>k5?k4:k5, m67=k6>k7?k6:k7;
    unsigned long long a=m01>m23?m01:m23, c2=m45>m67?m45:m67;
    unsigned long long best = a>c2?a:c2;
    unsigned long long o = __shfl_xor(best, 32);
    best = (o > best) ? o : best;
    return 255 - (int)(best & 0xFFull);
  };

  float chS = 0.f, fhS = 0.f;
  if (owner) {
    chS = h0[b*896 + jc];
    fhS = h0[b*896 + 448 + jc];
    unsigned* Hc = Hg + (b*56 + w)*16;
    store_half(Hc, 0, chS);
    store_half(Hc, 1, fhS);
  }
  drain();
  __syncthreads();
  if (tid == 0) xchg32(&fE0[w*16], 1u);
  if (wv == 0) wait56(fE0, 56, 1u);
  __syncthreads();

  float xcr=0, xcu=0, xce=0, xfr=0, xfu=0, xfe=0;
  auto prefetch = [&](int t){
    if (owner) {
      const float* cb_ = cond + ((size_t)b*TT + t)*2688;
      xcr = cb_[jc];        xcu = cb_[896 + jc];  xce = cb_[1792 + jc];
      xfr = cb_[448 + jc];  xfu = cb_[1344 + jc]; xfe = cb_[2240 + jc];
    }
  };
  // one K-half of the GRU GEMM for this wave's (g_mt, g_kh); plain cached H loads.
  auto gemm_half = [&](const unsigned* H, bool add){
    f32x4 ah0={0,0,0,0}, al0={0,0,0,0}, ah1={0,0,0,0}, al1={0,0,0,0};
    const unsigned* c0 = H + ((size_t)(l&15)*56 + (l>>4))*16 + g_kh*8;
    const unsigned* c1 = c0 + 16*56*16;
    #pragma unroll
    for (int ks=0; ks<14; ks++) {
      const unsigned* p0 = c0 + ks*64;
      const unsigned* p1 = c1 + ks*64;
      f16x8 bh0 = *(const f16x8*)(p0);
      f16x8 bl0 = *(const f16x8*)(p0 + 4);
      f16x8 bh1 = *(const f16x8*)(p1);
      f16x8 bl1 = *(const f16x8*)(p1 + 4);
      ah0 = __builtin_amdgcn_mfma_f32_16x16x32_f16(afh[ks], bh0, ah0, 0,0,0);
      al0 = __builtin_amdgcn_mfma_f32_16x16x32_f16(afh[ks], bl0, al0, 0,0,0);
      al0 = __builtin_amdgcn_mfma_f32_16x16x32_f16(afl[ks], bh0, al0, 0,0,0);
      ah1 = __builtin_amdgcn_mfma_f32_16x16x32_f16(afh[ks], bh1, ah1, 0,0,0);
      al1 = __builtin_amdgcn_mfma_f32_16x16x32_f16(afh[ks], bl1, al1, 0,0,0);
      al1 = __builtin_amdgcn_mfma_f32_16x16x32_f16(afl[ks], bh1, al1, 0,0,0);
    }
    #pragma unroll
    for (int i=0;i<4;i++){
      int row = g_mt*16 + (l>>4)*4 + i;
      float v0 = ah0[i] + al0[i]*INVSPLIT;
      float v1 = ah1[i] + al1[i]*INVSPLIT;
      if (!add) {
        hpL[row][l&15]      = v0 + hblL[row];
        hpL[row][16+(l&15)] = v1 + hblL[row];
      } else {
        hpL[row][l&15]      += v0;
        hpL[row][16+(l&15)] += v1;
      }
    }
  };
  // bins matmul: A-frag = one 16B chunk read per (batch row, k-slice); B from LDS
  auto do_bins = [&](const unsigned* H, int fine, const f16x8* Bh, const f16x8* Bl,
                     float bias, unsigned long long* part, unsigned tgt, int ntb){
    f32x4 acch={0,0,0,0}, accl={0,0,0,0};
    const unsigned* ar = H + ((size_t)(ntb*16 + (l&15))*56 + (l>>4))*16 + fine*8;
    #pragma unroll
    for (int ks=0; ks<14; ks++) {
      const unsigned* p = ar + ks*64;
      f16x8 ah  = *(const f16x8*)(p);
      f16x8 al_ = *(const f16x8*)(p + 4);
      f16x8 bh = Bh[ks*64 + l];
      f16x8 bl = Bl[ks*64 + l];
      acch = __builtin_amdgcn_mfma_f32_16x16x32_f16(ah,  bh, acch, 0,0,0);
      accl = __builtin_amdgcn_mfma_f32_16x16x32_f16(ah,  bl, accl, 0,0,0);
      accl = __builtin_amdgcn_mfma_f32_16x16x32_f16(al_, bh, accl, 0,0,0);
    }
    #pragma unroll
    for (int i=0;i<4;i++){
      unsigned long long key = amax_key(acch[i] + accl[i]*INVSPLIT + bias, w*16 + (l&15), tgt);
      #pragma unroll
      for (int m=1; m<16; m<<=1){
        unsigned long long o = __shfl_xor(key, m, 16);
        key = (o > key) ? o : key;
      }
      if ((l&15)==0) xchg64(&part[w*32 + ntb*16 + (l>>4)*4 + i], key);
    }
  };

  prefetch(0);
  // prologue: hp(0) (ch-half writes, fh-half adds)
  if (g_kh == 0) gemm_half(Hg, false);
  __syncthreads();
  if (g_kh == 1) gemm_half(Hg, true);
  __syncthreads();

  for (int t=0; t<TT; t++) {
    unsigned* Hn = Hg + (((t+1)&1) ? 28672 : 0);
    const unsigned tgt = (unsigned)(t+1);

    // ---- A: coarse elementwise + publish ch; stash fine-gate hp in registers ----
    float cprev = 0.f, fprev = 0.f, hfr_ = 0.f, hfu_ = 0.f, hfe_ = 0.f;
    if (owner) {
      cprev = coarseL[b]; fprev = fineL[b];
      float cpr = cprev*wclL[0][e][0] + fprev*wclL[0][e][1] + bclL[0][e] + xcr;
      float cpu_= cprev*wclL[1][e][0] + fprev*wclL[1][e][1] + bclL[1][e] + xcu;
      float cpe = cprev*wclL[2][e][0] + fprev*wclL[2][e][1] + bclL[2][e] + xce;
      float r  = sigacc(cpr  + hpL[e][b]);
      float u  = sigacc(cpu_ + hpL[8+e][b]);
      float g  = tanhf(fmaf(r, hpL[16+e][b], cpe));
      hfr_ = hpL[24+e][b]; hfu_ = hpL[32+e][b]; hfe_ = hpL[40+e][b];
      chS = fmaf(u, chS - g, g);
      store_half(Hn + (b*56 + w)*16, 0, chS);
    }
    drain();
    __syncthreads();
    if (tid == 0) xchg32(&fE1[w*16], tgt);
    if (wv == 0) wait56(fE1, 56, tgt);
    __syncthreads();

    // ---- coarse window: binsC (w<16, wv 0-1) | gemm-ch -> hpL (wv 2-4) | pollC (wv 5)
    if (w < 16 && wv < 2) do_bins(Hn, 0, binBh0, binBl0, biasC, partC, tgt, wv);
    if (g_kh == 0) gemm_half(Hn, false);
    if (wv == 5) {
      int bin = poll16(partC, tgt);
      if (l < 32) {
        coarseL[l] = (float)bin * (1.0f/127.5f) - 1.0f;
        if (w == 0) out[l*TT + t] = (float)bin;
      }
    }
    __syncthreads();

    // ---- D: fine elementwise (uses stashed gates) + publish fh ----
    if (owner) {
      float cnew = coarseL[b];
      float fpr = cprev*wflL[0][e][0] + fprev*wflL[0][e][1] + cnew*wflL[0][e][2] + bflL[0][e] + xfr;
      float fpu = cprev*wflL[1][e][0] + fprev*wflL[1][e][1] + cnew*wflL[1][e][2] + bflL[1][e] + xfu;
      float fpe = cprev*wflL[2][e][0] + fprev*wflL[2][e][1] + cnew*wflL[2][e][2] + bflL[2][e] + xfe;
      float r  = sigacc(fpr + hfr_);
      float u  = sigacc(fpu + hfu_);
      float g  = tanhf(fmaf(r, hfe_, fpe));
      fhS = fmaf(u, fhS - g, g);
      store_half(Hn + (b*56 + w)*16, 1, fhS);
    }
    drain();
    __syncthreads();
    if (tid == 0) xchg32(&fE3[w*16], tgt);
    if (t < TT-1) prefetch(t+1);
    if (wv == 0) wait56(fE3, 56, tgt);
    __syncthreads();

    // ---- fine window: binsF (w<16, wv 2-3) | gemm-fh += hpL (wv 0,1,5) | pollF (wv 4)
    if (w < 16 && (wv == 2 || wv == 3)) do_bins(Hn, 1, binBh1, binBl1, biasF, partF, tgt, wv-2);
    if (g_kh == 1) gemm_half(Hn, true);
    if (wv == 4) {
      int bin = poll16(partF, tgt);
      if (l < 32) {
        fineL[l] = (float)bin * (1.0f/127.5f) - 1.0f;
        if (w == 0) out[8192 + l*TT + t] = (float)bin;
      }
    }
    __syncthreads();
  }

  if (owner) {
    out[16384 + b*896 + jc]        = chS;
    out[16384 + b*896 + 448 + jc]  = fhS;
  }
}

// ---------------- ws layout (bytes) ----------------------------------------------
#define WS_AH    0u
#define WS_AL    4816896u
#define WS_BCH   9633792u
#define WS_BCL   9863168u
#define WS_BFH   10092544u
#define WS_BFL   10321920u
#define WS_HG    10551296u
#define WS_FLAGS 10780672u
#define WS_PC    10793984u
#define WS_PF    10798080u

extern "C" void kernel_launch(void* const* d_in, const int* in_sizes, int n_in,
                              void* d_out, int out_size, void* d_ws, size_t ws_size,
                              hipStream_t stream) {
  const float* conditional = (const float*)d_in[0];
  const float* hidden0     = (const float*)d_in[1];
  const float* gib         = (const float*)d_in[2];
  const float* ghw         = (const float*)d_in[3];
  const float* ghb         = (const float*)d_in[4];
  const float* wci         = (const float*)d_in[5];
  const float* bci         = (const float*)d_in[6];
  const float* wfi         = (const float*)d_in[7];
  const float* bfi         = (const float*)d_in[8];
  const float* wbc         = (const float*)d_in[9];
  const float* bbc         = (const float*)d_in[10];
  const float* wbf         = (const float*)d_in[11];
  const float* bbf         = (const float*)d_in[12];

  char* ws = (char*)d_ws;
  f16* wsAh  = (f16*)(ws + WS_AH);
  f16* wsAl  = (f16*)(ws + WS_AL);
  f16* wsBCh = (f16*)(ws + WS_BCH);
  f16* wsBCl = (f16*)(ws + WS_BCL);
  f16* wsBFh = (f16*)(ws + WS_BFH);
  f16* wsBFl = (f16*)(ws + WS_BFL);
  unsigned* Hg = (unsigned*)(ws + WS_HG);
  unsigned* flags = (unsigned*)(ws + WS_FLAGS);
  unsigned long long* partC = (unsigned long long*)(ws + WS_PC);
  unsigned long long* partF = (unsigned long long*)(ws + WS_PF);
  float* out = (float*)d_out;

  hipMemsetAsync(ws + WS_FLAGS, 0, 21504, stream);
  pack_gru<<<dim3(56*6*14), dim3(64), 0, stream>>>(ghw, wsAh, wsAl);
  pack_bins<<<dim3(448), dim3(64), 0, stream>>>(wbc, wbf, wsBCh, wsBCl, wsBFh, wsBFl);
  wavernn_main<<<dim3(NWG), dim3(NTHR), 0, stream>>>(
      conditional, hidden0, gib, ghb, wci, bci, wfi, bfi, bbc, bbf,
      wsAh, wsAl, wsBCh, wsBCl, wsBFh, wsBFl,
      Hg, partC, partF, flags, out);
}

// Round 12
// 5305.309 us; speedup vs baseline: 1.0896x; 1.0896x over previous
//
#include <hip/hip_runtime.h>

#define NWG  56
#define NBLK 57
#define NTHR 384
#define TT   256
#define SPLITF   2048.0f
#define INVSPLIT 4.8828125e-4f

typedef _Float16 f16;
typedef __attribute__((ext_vector_type(8))) _Float16 f16x8;
typedef __attribute__((ext_vector_type(4))) float f32x4;

__device__ __forceinline__ float sigacc(float x){ return 1.0f/(1.0f + expf(-x)); }

// key = [order-preserving f32 : 32][step tag : 16][255-bin : 8]
__device__ __forceinline__ unsigned long long amax_key(float v, int bin, unsigned tag){
  unsigned u = __float_as_uint(v);
  u = (u & 0x80000000u) ? ~u : (u | 0x80000000u);
  return ((unsigned long long)u << 32) | ((unsigned long long)(tag & 0xFFFFu) << 8)
       | (unsigned)(255 - bin);
}

// hp chunk bases {hcr,hcu,hce,hfr,hfu,hfe} = 448*{0,2,4,1,3,5}
__device__ __forceinline__ int grp_base(int g){ return 448 * ((g < 3) ? (2*g) : (2*g - 5)); }

// ---- cross-WG primitives (r4/r7-proven): writes RMW at LLC; polls relaxed agent.
__device__ __forceinline__ void xchg32(unsigned* p, unsigned v){
  __hip_atomic_exchange(p, v, __ATOMIC_RELAXED, __HIP_MEMORY_SCOPE_AGENT);
}
__device__ __forceinline__ void xchg64(unsigned long long* p, unsigned long long v){
  __hip_atomic_exchange(p, v, __ATOMIC_RELAXED, __HIP_MEMORY_SCOPE_AGENT);
}
__device__ __forceinline__ unsigned ldg32(const unsigned* p){
  return __hip_atomic_load(p, __ATOMIC_RELAXED, __HIP_MEMORY_SCOPE_AGENT);
}
__device__ __forceinline__ unsigned long long ldg64(const void* p){
  return __hip_atomic_load((const unsigned long long*)p, __ATOMIC_RELAXED, __HIP_MEMORY_SCOPE_AGENT);
}
__device__ __forceinline__ void drain(){ asm volatile("s_waitcnt vmcnt(0)" ::: "memory"); }
__device__ __forceinline__ int f16bits(f16 h){
  return (int)__builtin_bit_cast(unsigned short, h);
}

// ---- prep: pack GRU weight rows into MFMA A-fragment order, f16 hi/lo split ----
__global__ void pack_gru(const float* __restrict__ W, f16* __restrict__ outH, f16* __restrict__ outL){
  int blk = blockIdx.x;            // ((w*6 + (mt*2+kh))*14 + ks) ; 56*6*14 = 4704
  int ks  = blk % 14;
  int rest= blk / 14;
  int wv  = rest % 6, w = rest / 6;
  int mt  = wv >> 1, kh = wv & 1;
  int l   = threadIdx.x;
  int lr  = mt*16 + (l & 15);
  int R   = grp_base(lr >> 3) + 8*w + (lr & 7);
  int k   = kh*448 + ks*32 + (l >> 4)*8;
  const float* src = W + (size_t)R*896 + k;
  f16x8 vh, vl;
  #pragma unroll
  for (int i=0;i<8;i++){
    float x = src[i];
    f16 h = (f16)x;
    vh[i] = h;
    vl[i] = (f16)((x - (float)h) * SPLITF);
  }
  size_t o = (size_t)blk*64 + l;
  ((f16x8*)outH)[o] = vh;
  ((f16x8*)outL)[o] = vl;
}

// ---- prep: pack bins weights into MFMA B-fragment order, f16 hi/lo split -------
__global__ void pack_bins(const float* __restrict__ Wc, const float* __restrict__ Wf,
                          f16* __restrict__ oCh, f16* __restrict__ oCl,
                          f16* __restrict__ oFh, f16* __restrict__ oFl){
  int blk  = blockIdx.x;           // 2*16*14 = 448
  int half = blk / 224;
  int rem  = blk % 224;            // wg*14 + ks
  int ks   = rem % 14, wg = rem / 14;
  int l    = threadIdx.x;
  const float* W = half ? Wf : Wc;
  f16* oh = half ? oFh : oCh;
  f16* ol = half ? oFl : oCl;
  int bin = wg*16 + (l & 15);
  int k   = ks*32 + (l >> 4)*8;
  const float* src = W + (size_t)bin*448 + k;
  f16x8 vh, vl;
  #pragma unroll
  for (int i=0;i<8;i++){
    float x = src[i];
    f16 h = (f16)x;
    vh[i] = h;
    vl[i] = (f16)((x - (float)h) * SPLITF);
  }
  size_t o = (size_t)rem*64 + l;
  ((f16x8*)oh)[o] = vh;
  ((f16x8*)ol)[o] = vl;
}

// ---------------- main persistent kernel -----------------------------------------
// H layout (u32): [2 bufs][32 batch][56 wg][16]: per 64B chunk:
//   0..3 ch-hi pairs | 4..7 ch-lo | 8..11 fh-hi | 12..15 fh-lo
__launch_bounds__(NTHR, 1)
__global__ void wavernn_main(
    const float* __restrict__ cond,      // [32][256][3][896]
    const float* __restrict__ h0,        // [32][896]
    const float* __restrict__ gib,       // [2688]
    const float* __restrict__ ghb,       // [2688]
    const float* __restrict__ wci,       // [1344][2]
    const float* __restrict__ bci,       // [1344]
    const float* __restrict__ wfi,       // [1344][3]
    const float* __restrict__ bfi,       // [1344]
    const float* __restrict__ bbc,       // [256]
    const float* __restrict__ bbf,       // [256]
    const f16*  __restrict__ wsAh, const f16* __restrict__ wsAl,
    const f16*  __restrict__ wsBCh, const f16* __restrict__ wsBCl,
    const f16*  __restrict__ wsBFh, const f16* __restrict__ wsBFl,
    unsigned*   __restrict__ Hg,         // [2][32][56][16] u32
    unsigned long long* __restrict__ partC,   // [16][32] tagged keys
    unsigned long long* __restrict__ partF,   // [16][32]
    unsigned*   __restrict__ flags,      // fE0 @0, fE1 @1024, fE3 @2048 (u32, stride 16)
    unsigned*   __restrict__ resC,       // [32] tagged results, stride 16
    unsigned*   __restrict__ resF,       // [32] stride 16
    float* __restrict__ out)             // [8192 oc][8192 of][28672 hidden]
{
  __shared__ float hpL[48][33];
  __shared__ f16x8 binBh0[896], binBl0[896], binBh1[896], binBl1[896];
  __shared__ float wclL[3][8][2], bclL[3][8], wflL[3][8][3], bflL[3][8], hblL[48];

  const int w   = blockIdx.x;
  const int tid = threadIdx.x;
  const int wv  = tid >> 6;
  const int l   = tid & 63;

  // aggregator poll of 16 tagged partials for batch (l&31); returns max key (r7)
  auto poll_parts = [&](const unsigned long long* part, unsigned tgt)->unsigned long long {
    int bb = l & 31;
    unsigned long long k0,k1,k2,k3,k4,k5,k6,k7,k8,k9,k10,k11,k12,k13,k14,k15;
    for(;;){
      k0=ldg64(&part[0*32+bb]);  k1=ldg64(&part[1*32+bb]);
      k2=ldg64(&part[2*32+bb]);  k3=ldg64(&part[3*32+bb]);
      k4=ldg64(&part[4*32+bb]);  k5=ldg64(&part[5*32+bb]);
      k6=ldg64(&part[6*32+bb]);  k7=ldg64(&part[7*32+bb]);
      k8=ldg64(&part[8*32+bb]);  k9=ldg64(&part[9*32+bb]);
      k10=ldg64(&part[10*32+bb]); k11=ldg64(&part[11*32+bb]);
      k12=ldg64(&part[12*32+bb]); k13=ldg64(&part[13*32+bb]);
      k14=ldg64(&part[14*32+bb]); k15=ldg64(&part[15*32+bb]);
      unsigned long long tmask = 0xFFFF00ull, texp = (unsigned long long)tgt << 8;
      bool ok = ((k0&tmask)==texp) & ((k1&tmask)==texp) & ((k2&tmask)==texp) & ((k3&tmask)==texp)
              & ((k4&tmask)==texp) & ((k5&tmask)==texp) & ((k6&tmask)==texp) & ((k7&tmask)==texp)
              & ((k8&tmask)==texp) & ((k9&tmask)==texp) & ((k10&tmask)==texp)& ((k11&tmask)==texp)
              & ((k12&tmask)==texp)& ((k13&tmask)==texp)& ((k14&tmask)==texp)& ((k15&tmask)==texp);
      if (__all(ok)) break;
      __builtin_amdgcn_s_sleep(1);
    }
    unsigned long long m01=k0>k1?k0:k1, m23=k2>k3?k2:k3, m45=k4>k5?k4:k5, m67=k6>k7?k6:k7;
    unsigned long long m89=k8>k9?k8:k9, mab=k10>k11?k10:k11, mcd=k12>k13?k12:k13, mef=k14>k15?k14:k15;
    unsigned long long a=m01>m23?m01:m23, c2=m45>m67?m45:m67, d=m89>mab?m89:mab, f=mcd>mef?mcd:mef;
    unsigned long long x=a>c2?a:c2, y=d>f?d:f;
    return x>y?x:y;
  };

  // ---- dedicated aggregator WG (r7-proven): two independent waves ----
  if (w == NWG) {
    if (wv == 0) {
      for (int t=0; t<TT; t++){
        unsigned tgt = (unsigned)(t+1);
        unsigned long long best = poll_parts(partC, tgt);
        int bin = 255 - (int)(best & 0xFFull);
        if (l < 32) {
          xchg32(&resC[l*16], (tgt << 16) | (unsigned)bin);   // res FIRST
          out[l*TT + t] = (float)bin;
        }
      }
    } else if (wv == 1) {
      for (int t=0; t<TT; t++){
        unsigned tgt = (unsigned)(t+1);
        unsigned long long best = poll_parts(partF, tgt);
        int bin = 255 - (int)(best & 0xFFull);
        if (l < 32) {
          xchg32(&resF[l*16], (tgt << 16) | (unsigned)bin);
          out[8192 + l*TT + t] = (float)bin;
        }
      }
    }
    return;
  }

  const int b   = tid >> 3, e = tid & 7;
  const bool owner = tid < 256;
  const int jc  = 8*w + e;

  unsigned* fE0 = flags;
  unsigned* fE1 = flags + 1024;
  unsigned* fE3 = flags + 2048;

  // gemm role: waves 2,3,4 hold kh=0 (ch-half) frags; waves 0,1,5 hold kh=1 (fh-half)
  const int g_kh = (wv >= 2 && wv <= 4) ? 0 : 1;
  const int g_mt = (wv >= 2 && wv <= 4) ? (wv - 2) : (wv == 5 ? 2 : wv);

  // A fragments persistent in VGPRs: 16 rows x half-K, hi+lo
  f16x8 afh[14], afl[14];
  {
    const f16x8* Ah = (const f16x8*)wsAh + (size_t)(w*6 + (g_mt*2 + g_kh))*14*64;
    const f16x8* Al = (const f16x8*)wsAl + (size_t)(w*6 + (g_mt*2 + g_kh))*14*64;
    #pragma unroll
    for (int ks=0; ks<14; ks++){ afh[ks] = Ah[ks*64 + l]; afl[ks] = Al[ks*64 + l]; }
  }
  if (w < 16) {
    const f16x8* s0 = (const f16x8*)wsBCh + (size_t)w*896;
    const f16x8* s1 = (const f16x8*)wsBCl + (size_t)w*896;
    const f16x8* s2 = (const f16x8*)wsBFh + (size_t)w*896;
    const f16x8* s3 = (const f16x8*)wsBFl + (size_t)w*896;
    for (int i = tid; i < 896; i += NTHR) {
      binBh0[i] = s0[i]; binBl0[i] = s1[i];
      binBh1[i] = s2[i]; binBl1[i] = s3[i];
    }
  }
  if (tid < 48) hblL[tid] = ghb[grp_base(tid>>3) + 8*w + (tid&7)];
  if (tid < 24) {
    int p = tid >> 3, ee = tid & 7;
    int j = p*448 + 8*w + ee;
    wclL[p][ee][0] = wci[j*2+0]; wclL[p][ee][1] = wci[j*2+1];
    bclL[p][ee]    = bci[j] + gib[p*896 + 8*w + ee];
    wflL[p][ee][0] = wfi[j*3+0]; wflL[p][ee][1] = wfi[j*3+1]; wflL[p][ee][2] = wfi[j*3+2];
    bflL[p][ee]    = bfi[j] + gib[p*896 + 448 + 8*w + ee];
  }
  float biasC = 0.f, biasF = 0.f;
  if (w < 16) { biasC = bbc[w*16 + (l&15)]; biasF = bbf[w*16 + (l&15)]; }

  // pack+store into this WG's PRIVATE 64B chunk: 4 xchg64 per publish (e=0,4 lanes)
  auto store_half = [&](unsigned* Hc, int fine, float val){
    f16 hh = (f16)val;
    f16 hl = (f16)((val - (float)hh) * SPLITF);
    int pk = f16bits(hh) | (f16bits(hl) << 16);
    int n1 = __shfl_down(pk, 1);
    int n2 = __shfl_down(pk, 2);
    int n3 = __shfl_down(pk, 3);
    if ((e & 3) == 0) {
      unsigned h0_ = (unsigned)((pk & 0xffff) | (n1 << 16));
      unsigned h1_ = (unsigned)((n2 & 0xffff) | (n3 << 16));
      unsigned l0_ = ((unsigned)pk >> 16) | ((unsigned)n1 & 0xffff0000u);
      unsigned l1_ = ((unsigned)n2 >> 16) | ((unsigned)n3 & 0xffff0000u);
      int q = e >> 2;   // 0 or 1
      xchg64((unsigned long long*)(Hc + fine*8 + q*2),
             (unsigned long long)h0_ | ((unsigned long long)h1_ << 32));
      xchg64((unsigned long long*)(Hc + fine*8 + 4 + q*2),
             (unsigned long long)l0_ | ((unsigned long long)l1_ << 32));
    }
  };

  // flag poll: relaxed until detect, then ONE acquire load -> cache inv, so
  // subsequent PLAIN CACHED loads of the released data are safe (r7-proven).
  auto wait56 = [&](const unsigned* f, int n, unsigned tgt){
    const unsigned* p = f + ((l < n) ? l*16 : 0);
    for(;;){
      unsigned v = ldg32(p);
      if (__all(v == tgt)) break;
      __builtin_amdgcn_s_sleep(1);
    }
    unsigned vv = __hip_atomic_load(p, __ATOMIC_ACQUIRE, __HIP_MEMORY_SCOPE_AGENT);
    asm volatile("" :: "v"(vv) : "memory");
  };
  // owner-direct result poll: 8 lanes of a batch share res line b*16; uncached.
  auto poll_res_owner = [&](const unsigned* res, unsigned tgt)->float{
    const unsigned* p = res + b*16;
    unsigned v;
    for(;;){
      v = ldg32(p);
      if (__all((v >> 16) == tgt)) break;
      __builtin_amdgcn_s_sleep(1);
    }
    asm volatile("" ::: "memory");
    return (float)(int)(v & 0xFFFFu) * (1.0f/127.5f) - 1.0f;
  };

  float chS = 0.f, fhS = 0.f;
  if (owner) {
    chS = h0[b*896 + jc];
    fhS = h0[b*896 + 448 + jc];
    unsigned* Hc = Hg + (b*56 + w)*16;
    store_half(Hc, 0, chS);
    store_half(Hc, 1, fhS);
  }
  drain();
  __syncthreads();
  if (tid == 0) xchg32(&fE0[w*16], 1u);
  if (wv == 0) wait56(fE0, 56, 1u);
  __syncthreads();

  float xcr=0, xcu=0, xce=0, xfr=0, xfu=0, xfe=0;
  auto prefetch = [&](int t){
    if (owner) {
      const float* cb_ = cond + ((size_t)b*TT + t)*2688;
      xcr = cb_[jc];        xcu = cb_[896 + jc];  xce = cb_[1792 + jc];
      xfr = cb_[448 + jc];  xfu = cb_[1344 + jc]; xfe = cb_[2240 + jc];
    }
  };
  // one K-half of the GRU GEMM for this wave's (g_mt, g_kh); plain cached H loads.
  auto gemm_half = [&](const unsigned* H, bool add){
    f32x4 ah0={0,0,0,0}, al0={0,0,0,0}, ah1={0,0,0,0}, al1={0,0,0,0};
    const unsigned* c0 = H + ((size_t)(l&15)*56 + (l>>4))*16 + g_kh*8;
    const unsigned* c1 = c0 + 16*56*16;
    #pragma unroll
    for (int ks=0; ks<14; ks++) {
      const unsigned* p0 = c0 + ks*64;
      const unsigned* p1 = c1 + ks*64;
      f16x8 bh0 = *(const f16x8*)(p0);
      f16x8 bl0 = *(const f16x8*)(p0 + 4);
      f16x8 bh1 = *(const f16x8*)(p1);
      f16x8 bl1 = *(const f16x8*)(p1 + 4);
      ah0 = __builtin_amdgcn_mfma_f32_16x16x32_f16(afh[ks], bh0, ah0, 0,0,0);
      al0 = __builtin_amdgcn_mfma_f32_16x16x32_f16(afh[ks], bl0, al0, 0,0,0);
      al0 = __builtin_amdgcn_mfma_f32_16x16x32_f16(afl[ks], bh0, al0, 0,0,0);
      ah1 = __builtin_amdgcn_mfma_f32_16x16x32_f16(afh[ks], bh1, ah1, 0,0,0);
      al1 = __builtin_amdgcn_mfma_f32_16x16x32_f16(afh[ks], bl1, al1, 0,0,0);
      al1 = __builtin_amdgcn_mfma_f32_16x16x32_f16(afl[ks], bh1, al1, 0,0,0);
    }
    #pragma unroll
    for (int i=0;i<4;i++){
      int row = g_mt*16 + (l>>4)*4 + i;
      float v0 = ah0[i] + al0[i]*INVSPLIT;
      float v1 = ah1[i] + al1[i]*INVSPLIT;
      if (!add) {
        hpL[row][l&15]      = v0 + hblL[row];
        hpL[row][16+(l&15)] = v1 + hblL[row];
      } else {
        hpL[row][l&15]      += v0;
        hpL[row][16+(l&15)] += v1;
      }
    }
  };
  // bins matmul: A-frag = one 16B chunk read per (batch row, k-slice); B from LDS
  auto do_bins = [&](const unsigned* H, int fine, const f16x8* Bh, const f16x8* Bl,
                     float bias, unsigned long long* part, unsigned tgt, int ntb){
    f32x4 acch={0,0,0,0}, accl={0,0,0,0};
    const unsigned* ar = H + ((size_t)(ntb*16 + (l&15))*56 + (l>>4))*16 + fine*8;
    #pragma unroll
    for (int ks=0; ks<14; ks++) {
      const unsigned* p = ar + ks*64;
      f16x8 ah  = *(const f16x8*)(p);
      f16x8 al_ = *(const f16x8*)(p + 4);
      f16x8 bh = Bh[ks*64 + l];
      f16x8 bl = Bl[ks*64 + l];
      acch = __builtin_amdgcn_mfma_f32_16x16x32_f16(ah,  bh, acch, 0,0,0);
      accl = __builtin_amdgcn_mfma_f32_16x16x32_f16(ah,  bl, accl, 0,0,0);
      accl = __builtin_amdgcn_mfma_f32_16x16x32_f16(al_, bh, accl, 0,0,0);
    }
    #pragma unroll
    for (int i=0;i<4;i++){
      unsigned long long key = amax_key(acch[i] + accl[i]*INVSPLIT + bias, w*16 + (l&15), tgt);
      #pragma unroll
      for (int m=1; m<16; m<<=1){
        unsigned long long o = __shfl_xor(key, m, 16);
        key = (o > key) ? o : key;
      }
      if ((l&15)==0) xchg64(&part[w*32 + ntb*16 + (l>>4)*4 + i], key);
    }
  };

  prefetch(0);
  // prologue: hp(0) (ch-half writes, fh-half adds)
  if (g_kh == 0) gemm_half(Hg, false);
  __syncthreads();
  if (g_kh == 1) gemm_half(Hg, true);
  __syncthreads();

  float cprev = 128.0f/127.5f - 1.0f, fprev = -1.0f;
  for (int t=0; t<TT; t++) {
    unsigned* Hn = Hg + (((t+1)&1) ? 28672 : 0);
    const unsigned tgt = (unsigned)(t+1);

    // ---- A: owners get fprev(t-1) by direct poll; elementwise + publish ch;
    //      stash fine-gate hp rows in registers (hpL is overwritten next window)
    float hfr_ = 0.f, hfu_ = 0.f, hfe_ = 0.f;
    if (owner) {
      if (t > 0) fprev = poll_res_owner(resF, (unsigned)t);
      float cpr = cprev*wclL[0][e][0] + fprev*wclL[0][e][1] + bclL[0][e] + xcr;
      float cpu_= cprev*wclL[1][e][0] + fprev*wclL[1][e][1] + bclL[1][e] + xcu;
      float cpe = cprev*wclL[2][e][0] + fprev*wclL[2][e][1] + bclL[2][e] + xce;
      float r  = sigacc(cpr  + hpL[e][b]);
      float u  = sigacc(cpu_ + hpL[8+e][b]);
      float g  = tanhf(fmaf(r, hpL[16+e][b], cpe));
      hfr_ = hpL[24+e][b]; hfu_ = hpL[32+e][b]; hfe_ = hpL[40+e][b];
      chS = fmaf(u, chS - g, g);
      store_half(Hn + (b*56 + w)*16, 0, chS);
    }
    drain();
    __syncthreads();
    if (tid == 0) xchg32(&fE1[w*16], tgt);
    if (wv == 0) wait56(fE1, 56, tgt);
    __syncthreads();

    // ---- coarse window (no exit barrier): binsC (w<16, wv 0-1) | gemm-ch (wv 2-4)
    if (w < 16 && wv < 2) do_bins(Hn, 0, binBh0, binBl0, biasC, partC, tgt, wv);
    if (g_kh == 0) gemm_half(Hn, false);

    // ---- D: owners poll cnew directly; fine elementwise + publish fh ----
    if (owner) {
      float cnew = poll_res_owner(resC, tgt);
      float fpr = cprev*wflL[0][e][0] + fprev*wflL[0][e][1] + cnew*wflL[0][e][2] + bflL[0][e] + xfr;
      float fpu = cprev*wflL[1][e][0] + fprev*wflL[1][e][1] + cnew*wflL[1][e][2] + bflL[1][e] + xfu;
      float fpe = cprev*wflL[2][e][0] + fprev*wflL[2][e][1] + cnew*wflL[2][e][2] + bflL[2][e] + xfe;
      float r  = sigacc(fpr + hfr_);
      float u  = sigacc(fpu + hfu_);
      float g  = tanhf(fmaf(r, hfe_, fpe));
      fhS = fmaf(u, fhS - g, g);
      store_half(Hn + (b*56 + w)*16, 1, fhS);
      cprev = cnew;
    }
    drain();
    __syncthreads();
    if (tid == 0) xchg32(&fE3[w*16], tgt);
    if (t < TT-1) prefetch(t+1);
    if (wv == 0) wait56(fE3, 56, tgt);
    __syncthreads();

    // ---- fine window: binsF (w<16, wv 2-3) | gemm-fh += hpL (wv 0,1,5) ----
    if (w < 16 && (wv == 2 || wv == 3)) do_bins(Hn, 1, binBh1, binBl1, biasF, partF, tgt, wv-2);
    if (g_kh == 1) gemm_half(Hn, true);
    __syncthreads();   // hpL complete before A(t+1)
  }

  if (owner) {
    out[16384 + b*896 + jc]        = chS;
    out[16384 + b*896 + 448 + jc]  = fhS;
  }
}

// ---------------- ws layout (bytes) ----------------------------------------------
#define WS_AH    0u
#define WS_AL    4816896u
#define WS_BCH   9633792u
#define WS_BCL   9863168u
#define WS_BFH   10092544u
#define WS_BFL   10321920u
#define WS_HG    10551296u
#define WS_FLAGS 10780672u
#define WS_RES   10792960u
#define WS_PC    10797056u
#define WS_PF    10801152u

extern "C" void kernel_launch(void* const* d_in, const int* in_sizes, int n_in,
                              void* d_out, int out_size, void* d_ws, size_t ws_size,
                              hipStream_t stream) {
  const float* conditional = (const float*)d_in[0];
  const float* hidden0     = (const float*)d_in[1];
  const float* gib         = (const float*)d_in[2];
  const float* ghw         = (const float*)d_in[3];
  const float* ghb         = (const float*)d_in[4];
  const float* wci         = (const float*)d_in[5];
  const float* bci         = (const float*)d_in[6];
  const float* wfi         = (const float*)d_in[7];
  const float* bfi         = (const float*)d_in[8];
  const float* wbc         = (const float*)d_in[9];
  const float* bbc         = (const float*)d_in[10];
  const float* wbf         = (const float*)d_in[11];
  const float* bbf         = (const float*)d_in[12];

  char* ws = (char*)d_ws;
  f16* wsAh  = (f16*)(ws + WS_AH);
  f16* wsAl  = (f16*)(ws + WS_AL);
  f16* wsBCh = (f16*)(ws + WS_BCH);
  f16* wsBCl = (f16*)(ws + WS_BCL);
  f16* wsBFh = (f16*)(ws + WS_BFH);
  f16* wsBFl = (f16*)(ws + WS_BFL);
  unsigned* Hg = (unsigned*)(ws + WS_HG);
  unsigned* flags = (unsigned*)(ws + WS_FLAGS);
  unsigned* resC = (unsigned*)(ws + WS_RES);
  unsigned* resF = (unsigned*)(ws + WS_RES + 2048);
  unsigned long long* partC = (unsigned long long*)(ws + WS_PC);
  unsigned long long* partF = (unsigned long long*)(ws + WS_PF);
  float* out = (float*)d_out;

  hipMemsetAsync(ws + WS_FLAGS, 0, 24576, stream);
  pack_gru<<<dim3(56*6*14), dim3(64), 0, stream>>>(ghw, wsAh, wsAl);
  pack_bins<<<dim3(448), dim3(64), 0, stream>>>(wbc, wbf, wsBCh, wsBCl, wsBFh, wsBFl);
  wavernn_main<<<dim3(NBLK), dim3(NTHR), 0, stream>>>(
      conditional, hidden0, gib, ghb, wci, bci, wfi, bfi, bbc, bbf,
      wsAh, wsAl, wsBCh, wsBCl, wsBFh, wsBFl,
      Hg, partC, partF, flags, resC, resF, out);
}

// Round 13
// 5301.038 us; speedup vs baseline: 1.0905x; 1.0008x over previous
//
#include <hip/hip_runtime.h>

#define NWG  56
#define NBLK 57
#define NTHR 384
#define TT   256
#define SPLITF   2048.0f
#define INVSPLIT 4.8828125e-4f

typedef _Float16 f16;
typedef __attribute__((ext_vector_type(8))) _Float16 f16x8;
typedef __attribute__((ext_vector_type(4))) float f32x4;

__device__ __forceinline__ float sigacc(float x){ return 1.0f/(1.0f + expf(-x)); }

// key = [order-preserving f32 : 32][step tag : 16][255-bin : 8]
__device__ __forceinline__ unsigned long long amax_key(float v, int bin, unsigned tag){
  unsigned u = __float_as_uint(v);
  u = (u & 0x80000000u) ? ~u : (u | 0x80000000u);
  return ((unsigned long long)u << 32) | ((unsigned long long)(tag & 0xFFFFu) << 8)
       | (unsigned)(255 - bin);
}

// hp chunk bases {hcr,hcu,hce,hfr,hfu,hfe} = 448*{0,2,4,1,3,5}
__device__ __forceinline__ int grp_base(int g){ return 448 * ((g < 3) ? (2*g) : (2*g - 5)); }

// ---- cross-WG primitives (r4/r7-proven): writes RMW at LLC; polls relaxed agent.
__device__ __forceinline__ void xchg32(unsigned* p, unsigned v){
  __hip_atomic_exchange(p, v, __ATOMIC_RELAXED, __HIP_MEMORY_SCOPE_AGENT);
}
__device__ __forceinline__ void xchg64(unsigned long long* p, unsigned long long v){
  __hip_atomic_exchange(p, v, __ATOMIC_RELAXED, __HIP_MEMORY_SCOPE_AGENT);
}
__device__ __forceinline__ unsigned ldg32(const unsigned* p){
  return __hip_atomic_load(p, __ATOMIC_RELAXED, __HIP_MEMORY_SCOPE_AGENT);
}
__device__ __forceinline__ unsigned long long ldg64(const void* p){
  return __hip_atomic_load((const unsigned long long*)p, __ATOMIC_RELAXED, __HIP_MEMORY_SCOPE_AGENT);
}
__device__ __forceinline__ void drain(){ asm volatile("s_waitcnt vmcnt(0)" ::: "memory"); }
__device__ __forceinline__ int f16bits(f16 h){
  return (int)__builtin_bit_cast(unsigned short, h);
}

// ---- prep: pack GRU weight rows into MFMA A-fragment order, f16 hi/lo split ----
__global__ void pack_gru(const float* __restrict__ W, f16* __restrict__ outH, f16* __restrict__ outL){
  int blk = blockIdx.x;            // ((w*6 + (mt*2+kh))*14 + ks) ; 56*6*14 = 4704
  int ks  = blk % 14;
  int rest= blk / 14;
  int wv  = rest % 6, w = rest / 6;
  int mt  = wv >> 1, kh = wv & 1;
  int l   = threadIdx.x;
  int lr  = mt*16 + (l & 15);
  int R   = grp_base(lr >> 3) + 8*w + (lr & 7);
  int k   = kh*448 + ks*32 + (l >> 4)*8;
  const float* src = W + (size_t)R*896 + k;
  f16x8 vh, vl;
  #pragma unroll
  for (int i=0;i<8;i++){
    float x = src[i];
    f16 h = (f16)x;
    vh[i] = h;
    vl[i] = (f16)((x - (float)h) * SPLITF);
  }
  size_t o = (size_t)blk*64 + l;
  ((f16x8*)outH)[o] = vh;
  ((f16x8*)outL)[o] = vl;
}

// ---- prep: pack bins weights into MFMA B-fragment order, f16 hi/lo split -------
__global__ void pack_bins(const float* __restrict__ Wc, const float* __restrict__ Wf,
                          f16* __restrict__ oCh, f16* __restrict__ oCl,
                          f16* __restrict__ oFh, f16* __restrict__ oFl){
  int blk  = blockIdx.x;           // 2*16*14 = 448
  int half = blk / 224;
  int rem  = blk % 224;            // wg*14 + ks
  int ks   = rem % 14, wg = rem / 14;
  int l    = threadIdx.x;
  const float* W = half ? Wf : Wc;
  f16* oh = half ? oFh : oCh;
  f16* ol = half ? oFl : oCl;
  int bin = wg*16 + (l & 15);
  int k   = ks*32 + (l >> 4)*8;
  const float* src = W + (size_t)bin*448 + k;
  f16x8 vh, vl;
  #pragma unroll
  for (int i=0;i<8;i++){
    float x = src[i];
    f16 h = (f16)x;
    vh[i] = h;
    vl[i] = (f16)((x - (float)h) * SPLITF);
  }
  size_t o = (size_t)rem*64 + l;
  ((f16x8*)oh)[o] = vh;
  ((f16x8*)ol)[o] = vl;
}

// ---------------- main persistent kernel -----------------------------------------
// H layout (u32): [2 bufs][32 batch][56 wg][16]: per 64B chunk:
//   0..3 ch-hi pairs | 4..7 ch-lo | 8..11 fh-hi | 12..15 fh-lo
__launch_bounds__(NTHR, 1)
__global__ void wavernn_main(
    const float* __restrict__ cond,      // [32][256][3][896]
    const float* __restrict__ h0,        // [32][896]
    const float* __restrict__ gib,       // [2688]
    const float* __restrict__ ghb,       // [2688]
    const float* __restrict__ wci,       // [1344][2]
    const float* __restrict__ bci,       // [1344]
    const float* __restrict__ wfi,       // [1344][3]
    const float* __restrict__ bfi,       // [1344]
    const float* __restrict__ bbc,       // [256]
    const float* __restrict__ bbf,       // [256]
    const f16*  __restrict__ wsAh, const f16* __restrict__ wsAl,
    const f16*  __restrict__ wsBCh, const f16* __restrict__ wsBCl,
    const f16*  __restrict__ wsBFh, const f16* __restrict__ wsBFl,
    unsigned*   __restrict__ Hg,         // [2][32][56][16] u32
    unsigned long long* __restrict__ partC,   // [16][32] tagged keys
    unsigned long long* __restrict__ partF,   // [16][32]
    unsigned*   __restrict__ flags,      // fE0 @0, fE1 @1024, fE3 @2048 (u32, stride 16)
    unsigned*   __restrict__ resC,       // [32] tagged results, stride 16
    unsigned*   __restrict__ resF,       // [32] stride 16
    float* __restrict__ out)             // [8192 oc][8192 of][28672 hidden]
{
  __shared__ float hpL[48][33];
  __shared__ f16x8 binBh0[896], binBl0[896], binBh1[896], binBl1[896];
  __shared__ float wclL[3][8][2], bclL[3][8], wflL[3][8][3], bflL[3][8], hblL[48];

  const int w   = blockIdx.x;
  const int tid = threadIdx.x;
  const int wv  = tid >> 6;
  const int l   = tid & 63;

  // aggregator poll of 16 tagged partials for batch (l&31); returns max key (r7)
  auto poll_parts = [&](const unsigned long long* part, unsigned tgt)->unsigned long long {
    int bb = l & 31;
    unsigned long long k0,k1,k2,k3,k4,k5,k6,k7,k8,k9,k10,k11,k12,k13,k14,k15;
    for(;;){
      k0=ldg64(&part[0*32+bb]);  k1=ldg64(&part[1*32+bb]);
      k2=ldg64(&part[2*32+bb]);  k3=ldg64(&part[3*32+bb]);
      k4=ldg64(&part[4*32+bb]);  k5=ldg64(&part[5*32+bb]);
      k6=ldg64(&part[6*32+bb]);  k7=ldg64(&part[7*32+bb]);
      k8=ldg64(&part[8*32+bb]);  k9=ldg64(&part[9*32+bb]);
      k10=ldg64(&part[10*32+bb]); k11=ldg64(&part[11*32+bb]);
      k12=ldg64(&part[12*32+bb]); k13=ldg64(&part[13*32+bb]);
      k14=ldg64(&part[14*32+bb]); k15=ldg64(&part[15*32+bb]);
      unsigned long long tmask = 0xFFFF00ull, texp = (unsigned long long)tgt << 8;
      bool ok = ((k0&tmask)==texp) & ((k1&tmask)==texp) & ((k2&tmask)==texp) & ((k3&tmask)==texp)
              & ((k4&tmask)==texp) & ((k5&tmask)==texp) & ((k6&tmask)==texp) & ((k7&tmask)==texp)
              & ((k8&tmask)==texp) & ((k9&tmask)==texp) & ((k10&tmask)==texp)& ((k11&tmask)==texp)
              & ((k12&tmask)==texp)& ((k13&tmask)==texp)& ((k14&tmask)==texp)& ((k15&tmask)==texp);
      if (__all(ok)) break;
    }
    unsigned long long m01=k0>k1?k0:k1, m23=k2>k3?k2:k3, m45=k4>k5?k4:k5, m67=k6>k7?k6:k7;
    unsigned long long m89=k8>k9?k8:k9, mab=k10>k11?k10:k11, mcd=k12>k13?k12:k13, mef=k14>k15?k14:k15;
    unsigned long long a=m01>m23?m01:m23, c2=m45>m67?m45:m67, d=m89>mab?m89:mab, f=mcd>mef?mcd:mef;
    unsigned long long x=a>c2?a:c2, y=d>f?d:f;
    return x>y?x:y;
  };

  // ---- dedicated aggregator WG (r7-proven): two independent waves ----
  if (w == NWG) {
    if (wv == 0) {
      for (int t=0; t<TT; t++){
        unsigned tgt = (unsigned)(t+1);
        unsigned long long best = poll_parts(partC, tgt);
        int bin = 255 - (int)(best & 0xFFull);
        if (l < 32) {
          xchg32(&resC[l*16], (tgt << 16) | (unsigned)bin);   // res FIRST
          out[l*TT + t] = (float)bin;
        }
      }
    } else if (wv == 1) {
      for (int t=0; t<TT; t++){
        unsigned tgt = (unsigned)(t+1);
        unsigned long long best = poll_parts(partF, tgt);
        int bin = 255 - (int)(best & 0xFFull);
        if (l < 32) {
          xchg32(&resF[l*16], (tgt << 16) | (unsigned)bin);
          out[8192 + l*TT + t] = (float)bin;
        }
      }
    }
    return;
  }

  const int b   = tid >> 3, e = tid & 7;
  const bool owner = tid < 256;
  const int jc  = 8*w + e;

  unsigned* fE0 = flags;
  unsigned* fE1 = flags + 1024;
  unsigned* fE3 = flags + 2048;

  // gemm role: waves 2,3,4 hold kh=0 (ch-half) frags; waves 0,1,5 hold kh=1 (fh-half)
  const int g_kh = (wv >= 2 && wv <= 4) ? 0 : 1;
  const int g_mt = (wv >= 2 && wv <= 4) ? (wv - 2) : (wv == 5 ? 2 : wv);

  // A fragments persistent in VGPRs: 16 rows x half-K, hi+lo
  f16x8 afh[14], afl[14];
  {
    const f16x8* Ah = (const f16x8*)wsAh + (size_t)(w*6 + (g_mt*2 + g_kh))*14*64;
    const f16x8* Al = (const f16x8*)wsAl + (size_t)(w*6 + (g_mt*2 + g_kh))*14*64;
    #pragma unroll
    for (int ks=0; ks<14; ks++){ afh[ks] = Ah[ks*64 + l]; afl[ks] = Al[ks*64 + l]; }
  }
  if (w < 16) {
    const f16x8* s0 = (const f16x8*)wsBCh + (size_t)w*896;
    const f16x8* s1 = (const f16x8*)wsBCl + (size_t)w*896;
    const f16x8* s2 = (const f16x8*)wsBFh + (size_t)w*896;
    const f16x8* s3 = (const f16x8*)wsBFl + (size_t)w*896;
    for (int i = tid; i < 896; i += NTHR) {
      binBh0[i] = s0[i]; binBl0[i] = s1[i];
      binBh1[i] = s2[i]; binBl1[i] = s3[i];
    }
  }
  if (tid < 48) hblL[tid] = ghb[grp_base(tid>>3) + 8*w + (tid&7)];
  if (tid < 24) {
    int p = tid >> 3, ee = tid & 7;
    int j = p*448 + 8*w + ee;
    wclL[p][ee][0] = wci[j*2+0]; wclL[p][ee][1] = wci[j*2+1];
    bclL[p][ee]    = bci[j] + gib[p*896 + 8*w + ee];
    wflL[p][ee][0] = wfi[j*3+0]; wflL[p][ee][1] = wfi[j*3+1]; wflL[p][ee][2] = wfi[j*3+2];
    bflL[p][ee]    = bfi[j] + gib[p*896 + 448 + 8*w + ee];
  }
  float biasC = 0.f, biasF = 0.f;
  if (w < 16) { biasC = bbc[w*16 + (l&15)]; biasF = bbf[w*16 + (l&15)]; }

  // pack+store into this WG's PRIVATE 64B chunk: 4 xchg64 per publish (e=0,4 lanes)
  auto store_half = [&](unsigned* Hc, int fine, float val){
    f16 hh = (f16)val;
    f16 hl = (f16)((val - (float)hh) * SPLITF);
    int pk = f16bits(hh) | (f16bits(hl) << 16);
    int n1 = __shfl_down(pk, 1);
    int n2 = __shfl_down(pk, 2);
    int n3 = __shfl_down(pk, 3);
    if ((e & 3) == 0) {
      unsigned h0_ = (unsigned)((pk & 0xffff) | (n1 << 16));
      unsigned h1_ = (unsigned)((n2 & 0xffff) | (n3 << 16));
      unsigned l0_ = ((unsigned)pk >> 16) | ((unsigned)n1 & 0xffff0000u);
      unsigned l1_ = ((unsigned)n2 >> 16) | ((unsigned)n3 & 0xffff0000u);
      int q = e >> 2;   // 0 or 1
      xchg64((unsigned long long*)(Hc + fine*8 + q*2),
             (unsigned long long)h0_ | ((unsigned long long)h1_ << 32));
      xchg64((unsigned long long*)(Hc + fine*8 + 4 + q*2),
             (unsigned long long)l0_ | ((unsigned long long)l1_ << 32));
    }
  };

  // flag poll: relaxed until detect, then ONE acquire load -> cache inv, so
  // subsequent PLAIN CACHED loads of the released data are safe (r7-proven).
  auto wait56 = [&](const unsigned* f, int n, unsigned tgt){
    const unsigned* p = f + ((l < n) ? l*16 : 0);
    for(;;){
      unsigned v = ldg32(p);
      if (__all(v == tgt)) break;
    }
    unsigned vv = __hip_atomic_load(p, __ATOMIC_ACQUIRE, __HIP_MEMORY_SCOPE_AGENT);
    asm volatile("" :: "v"(vv) : "memory");
  };
  // owner-direct result poll: 8 lanes of a batch share res line b*16; uncached.
  auto poll_res_owner = [&](const unsigned* res, unsigned tgt)->float{
    const unsigned* p = res + b*16;
    unsigned v;
    for(;;){
      v = ldg32(p);
      if (__all((v >> 16) == tgt)) break;
    }
    asm volatile("" ::: "memory");
    return (float)(int)(v & 0xFFFFu) * (1.0f/127.5f) - 1.0f;
  };

  float chS = 0.f, fhS = 0.f;
  if (owner) {
    chS = h0[b*896 + jc];
    fhS = h0[b*896 + 448 + jc];
    unsigned* Hc = Hg + (b*56 + w)*16;
    store_half(Hc, 0, chS);
    store_half(Hc, 1, fhS);
  }
  drain();
  __syncthreads();
  if (tid == 0) xchg32(&fE0[w*16], 1u);
  if (wv == 0) wait56(fE0, 56, 1u);
  __syncthreads();

  float xcr=0, xcu=0, xce=0, xfr=0, xfu=0, xfe=0;
  auto prefetch = [&](int t){
    if (owner) {
      const float* cb_ = cond + ((size_t)b*TT + t)*2688;
      xcr = cb_[jc];        xcu = cb_[896 + jc];  xce = cb_[1792 + jc];
      xfr = cb_[448 + jc];  xfu = cb_[1344 + jc]; xfe = cb_[2240 + jc];
    }
  };
  // one K-half of the GRU GEMM for this wave's (g_mt, g_kh); plain cached H loads.
  auto gemm_half = [&](const unsigned* H, bool add){
    f32x4 ah0={0,0,0,0}, al0={0,0,0,0}, ah1={0,0,0,0}, al1={0,0,0,0};
    const unsigned* c0 = H + ((size_t)(l&15)*56 + (l>>4))*16 + g_kh*8;
    const unsigned* c1 = c0 + 16*56*16;
    #pragma unroll
    for (int ks=0; ks<14; ks++) {
      const unsigned* p0 = c0 + ks*64;
      const unsigned* p1 = c1 + ks*64;
      f16x8 bh0 = *(const f16x8*)(p0);
      f16x8 bl0 = *(const f16x8*)(p0 + 4);
      f16x8 bh1 = *(const f16x8*)(p1);
      f16x8 bl1 = *(const f16x8*)(p1 + 4);
      ah0 = __builtin_amdgcn_mfma_f32_16x16x32_f16(afh[ks], bh0, ah0, 0,0,0);
      al0 = __builtin_amdgcn_mfma_f32_16x16x32_f16(afh[ks], bl0, al0, 0,0,0);
      al0 = __builtin_amdgcn_mfma_f32_16x16x32_f16(afl[ks], bh0, al0, 0,0,0);
      ah1 = __builtin_amdgcn_mfma_f32_16x16x32_f16(afh[ks], bh1, ah1, 0,0,0);
      al1 = __builtin_amdgcn_mfma_f32_16x16x32_f16(afh[ks], bl1, al1, 0,0,0);
      al1 = __builtin_amdgcn_mfma_f32_16x16x32_f16(afl[ks], bh1, al1, 0,0,0);
    }
    #pragma unroll
    for (int i=0;i<4;i++){
      int row = g_mt*16 + (l>>4)*4 + i;
      float v0 = ah0[i] + al0[i]*INVSPLIT;
      float v1 = ah1[i] + al1[i]*INVSPLIT;
      if (!add) {
        hpL[row][l&15]      = v0 + hblL[row];
        hpL[row][16+(l&15)] = v1 + hblL[row];
      } else {
        hpL[row][l&15]      += v0;
        hpL[row][16+(l&15)] += v1;
      }
    }
  };
  // bins matmul: A-frag = one 16B chunk read per (batch row, k-slice); B from LDS
  auto do_bins = [&](const unsigned* H, int fine, const f16x8* Bh, const f16x8* Bl,
                     float bias, unsigned long long* part, unsigned tgt, int ntb){
    f32x4 acch={0,0,0,0}, accl={0,0,0,0};
    const unsigned* ar = H + ((size_t)(ntb*16 + (l&15))*56 + (l>>4))*16 + fine*8;
    #pragma unroll
    for (int ks=0; ks<14; ks++) {
      const unsigned* p = ar + ks*64;
      f16x8 ah  = *(const f16x8*)(p);
      f16x8 al_ = *(const f16x8*)(p + 4);
      f16x8 bh = Bh[ks*64 + l];
      f16x8 bl = Bl[ks*64 + l];
      acch = __builtin_amdgcn_mfma_f32_16x16x32_f16(ah,  bh, acch, 0,0,0);
      accl = __builtin_amdgcn_mfma_f32_16x16x32_f16(ah,  bl, accl, 0,0,0);
      accl = __builtin_amdgcn_mfma_f32_16x16x32_f16(al_, bh, accl, 0,0,0);
    }
    #pragma unroll
    for (int i=0;i<4;i++){
      unsigned long long key = amax_key(acch[i] + accl[i]*INVSPLIT + bias, w*16 + (l&15), tgt);
      #pragma unroll
      for (int m=1; m<16; m<<=1){
        unsigned long long o = __shfl_xor(key, m, 16);
        key = (o > key) ? o : key;
      }
      if ((l&15)==0) xchg64(&part[w*32 + ntb*16 + (l>>4)*4 + i], key);
    }
  };

  prefetch(0);
  // prologue: hp(0) (ch-half writes, fh-half adds)
  if (g_kh == 0) gemm_half(Hg, false);
  __syncthreads();
  if (g_kh == 1) gemm_half(Hg, true);
  __syncthreads();

  float cprev = 128.0f/127.5f - 1.0f, fprev = -1.0f;
  for (int t=0; t<TT; t++) {
    unsigned* Hn = Hg + (((t+1)&1) ? 28672 : 0);
    const unsigned tgt = (unsigned)(t+1);

    // ---- A: owners get fprev(t-1) by direct poll; elementwise + publish ch;
    //      stash fine-gate hp rows in registers (hpL is overwritten next window)
    float hfr_ = 0.f, hfu_ = 0.f, hfe_ = 0.f;
    if (owner) {
      if (t > 0) fprev = poll_res_owner(resF, (unsigned)t);
      float cpr = cprev*wclL[0][e][0] + fprev*wclL[0][e][1] + bclL[0][e] + xcr;
      float cpu_= cprev*wclL[1][e][0] + fprev*wclL[1][e][1] + bclL[1][e] + xcu;
      float cpe = cprev*wclL[2][e][0] + fprev*wclL[2][e][1] + bclL[2][e] + xce;
      float r  = sigacc(cpr  + hpL[e][b]);
      float u  = sigacc(cpu_ + hpL[8+e][b]);
      float g  = tanhf(fmaf(r, hpL[16+e][b], cpe));
      hfr_ = hpL[24+e][b]; hfu_ = hpL[32+e][b]; hfe_ = hpL[40+e][b];
      chS = fmaf(u, chS - g, g);
      store_half(Hn + (b*56 + w)*16, 0, chS);
    }
    drain();
    __syncthreads();
    if (tid == 0) xchg32(&fE1[w*16], tgt);
    if (wv == 0) wait56(fE1, 56, tgt);
    __syncthreads();

    // ---- coarse window (no exit barrier): binsC (w<16, wv 0-1) | gemm-ch (wv 2-4)
    if (w < 16 && wv < 2) do_bins(Hn, 0, binBh0, binBl0, biasC, partC, tgt, wv);
    if (g_kh == 0) gemm_half(Hn, false);

    // ---- D: owners poll cnew directly; fine elementwise + publish fh ----
    if (owner) {
      float cnew = poll_res_owner(resC, tgt);
      float fpr = cprev*wflL[0][e][0] + fprev*wflL[0][e][1] + cnew*wflL[0][e][2] + bflL[0][e] + xfr;
      float fpu = cprev*wflL[1][e][0] + fprev*wflL[1][e][1] + cnew*wflL[1][e][2] + bflL[1][e] + xfu;
      float fpe = cprev*wflL[2][e][0] + fprev*wflL[2][e][1] + cnew*wflL[2][e][2] + bflL[2][e] + xfe;
      float r  = sigacc(fpr + hfr_);
      float u  = sigacc(fpu + hfu_);
      float g  = tanhf(fmaf(r, hfe_, fpe));
      fhS = fmaf(u, fhS - g, g);
      store_half(Hn + (b*56 + w)*16, 1, fhS);
      cprev = cnew;
    }
    drain();
    __syncthreads();
    if (tid == 0) xchg32(&fE3[w*16], tgt);
    if (t < TT-1) prefetch(t+1);
    if (wv == 0) wait56(fE3, 56, tgt);
    __syncthreads();

    // ---- fine window: binsF (w<16, wv 2-3) | gemm-fh += hpL (wv 0,1,5) ----
    if (w < 16 && (wv == 2 || wv == 3)) do_bins(Hn, 1, binBh1, binBl1, biasF, partF, tgt, wv-2);
    if (g_kh == 1) gemm_half(Hn, true);
    __syncthreads();   // hpL complete before A(t+1)
  }

  if (owner) {
    out[16384 + b*896 + jc]        = chS;
    out[16384 + b*896 + 448 + jc]  = fhS;
  }
}

// ---------------- ws layout (bytes) ----------------------------------------------
#define WS_AH    0u
#define WS_AL    4816896u
#define WS_BCH   9633792u
#define WS_BCL   9863168u
#define WS_BFH   10092544u
#define WS_BFL   10321920u
#define WS_HG    10551296u
#define WS_FLAGS 10780672u
#define WS_RES   10792960u
#define WS_PC    10797056u
#define WS_PF    10801152u

extern "C" void kernel_launch(void* const* d_in, const int* in_sizes, int n_in,
                              void* d_out, int out_size, void* d_ws, size_t ws_size,
                              hipStream_t stream) {
  const float* conditional = (const float*)d_in[0];
  const float* hidden0     = (const float*)d_in[1];
  const float* gib         = (const float*)d_in[2];
  const float* ghw         = (const float*)d_in[3];
  const float* ghb         = (const float*)d_in[4];
  const float* wci         = (const float*)d_in[5];
  const float* bci         = (const float*)d_in[6];
  const float* wfi         = (const float*)d_in[7];
  const float* bfi         = (const float*)d_in[8];
  const float* wbc         = (const float*)d_in[9];
  const float* bbc         = (const float*)d_in[10];
  const float* wbf         = (const float*)d_in[11];
  const float* bbf         = (const float*)d_in[12];

  char* ws = (char*)d_ws;
  f16* wsAh  = (f16*)(ws + WS_AH);
  f16* wsAl  = (f16*)(ws + WS_AL);
  f16* wsBCh = (f16*)(ws + WS_BCH);
  f16* wsBCl = (f16*)(ws + WS_BCL);
  f16* wsBFh = (f16*)(ws + WS_BFH);
  f16* wsBFl = (f16*)(ws + WS_BFL);
  unsigned* Hg = (unsigned*)(ws + WS_HG);
  unsigned* flags = (unsigned*)(ws + WS_FLAGS);
  unsigned* resC = (unsigned*)(ws + WS_RES);
  unsigned* resF = (unsigned*)(ws + WS_RES + 2048);
  unsigned long long* partC = (unsigned long long*)(ws + WS_PC);
  unsigned long long* partF = (unsigned long long*)(ws + WS_PF);
  float* out = (float*)d_out;

  hipMemsetAsync(ws + WS_FLAGS, 0, 24576, stream);
  pack_gru<<<dim3(56*6*14), dim3(64), 0, stream>>>(ghw, wsAh, wsAl);
  pack_bins<<<dim3(448), dim3(64), 0, stream>>>(wbc, wbf, wsBCh, wsBCl, wsBFh, wsBFl);
  wavernn_main<<<dim3(NBLK), dim3(NTHR), 0, stream>>>(
      conditional, hidden0, gib, ghb, wci, bci, wfi, bfi, bbc, bbf,
      wsAh, wsAl, wsBCh, wsBCl, wsBFh, wsBFl,
      Hg, partC, partF, flags, resC, resF, out);
}